// Round 3
// baseline (615.412 us; speedup 1.0000x reference)
//
#include <hip/hip_runtime.h>

#define BLOCK 256
#define ROWS_PER_BLOCK 256
#define C 128
#define SEGS 32   // C/4 float4 segments per row

// Streaming variant: read ALL of predicts with perfectly coalesced float4
// loads (512 MB @ ~6.3 TB/s), pick the labeled element per row.
// Rationale: the gather touches 1 cache line per 512 B row; DRAM page-bound
// throughput for that pattern ~= streaming the whole array, and streaming is
// guaranteed to run at the measured 6.3 TB/s ceiling.
__global__ __launch_bounds__(BLOCK) void ce_stream_kernel(
    const float* __restrict__ predicts,
    const int* __restrict__ labels,
    float* __restrict__ partial,   // [gridDim.x]
    int n)
{
    __shared__ int lds_lab[ROWS_PER_BLOCK];
    const int row0 = blockIdx.x * ROWS_PER_BLOCK;

    // Stage this block's 256 labels into LDS (one coalesced load).
    {
        const int g = row0 + threadIdx.x;
        lds_lab[threadIdx.x] = (g < n) ? labels[g] : 0;
    }
    __syncthreads();

    float s = 0.0f;
    // 256 rows * 32 segs = 8192 (row,seg) pairs; 256 threads -> 32 iters.
    // Consecutive threads -> consecutive segs -> coalesced float4 loads.
    #pragma unroll 8
    for (int j = 0; j < (ROWS_PER_BLOCK * SEGS) / BLOCK; ++j) {
        const int f = j * BLOCK + threadIdx.x;
        const int row_local = f >> 5;
        const int seg = f & 31;
        const int g = row0 + row_local;
        if (g < n) {
            const float4 p = *reinterpret_cast<const float4*>(
                predicts + (size_t)g * C + seg * 4);
            const int lab = lds_lab[row_local];
            if ((lab >> 2) == seg) {
                const float v = (lab & 2) ? ((lab & 1) ? p.w : p.z)
                                          : ((lab & 1) ? p.y : p.x);
                s += __logf(v);
            }
        }
    }

    // Wave (64-lane) shuffle reduction.
    #pragma unroll
    for (int off = 32; off > 0; off >>= 1)
        s += __shfl_down(s, off, 64);

    __shared__ float wave_sums[BLOCK / 64];
    const int lane = threadIdx.x & 63;
    const int wv   = threadIdx.x >> 6;
    if (lane == 0) wave_sums[wv] = s;
    __syncthreads();

    if (threadIdx.x == 0) {
        partial[blockIdx.x] =
            wave_sums[0] + wave_sums[1] + wave_sums[2] + wave_sums[3];
    }
}

// Stage 2: reduce per-block partials; single plain store (no atomics/memset).
__global__ __launch_bounds__(256) void ce_final_kernel(
    const float* __restrict__ partial, int nparts,
    float neg_inv_n, float* __restrict__ out)
{
    float s = 0.0f;
    for (int i = threadIdx.x; i < nparts; i += 256)
        s += partial[i];

    #pragma unroll
    for (int off = 32; off > 0; off >>= 1)
        s += __shfl_down(s, off, 64);

    __shared__ float wave_sums[4];
    const int lane = threadIdx.x & 63;
    const int wv   = threadIdx.x >> 6;
    if (lane == 0) wave_sums[wv] = s;
    __syncthreads();

    if (threadIdx.x == 0) {
        out[0] = (wave_sums[0] + wave_sums[1] + wave_sums[2] + wave_sums[3])
                 * neg_inv_n;   // loss = -(1/N) * sum(log p)
    }
}

extern "C" void kernel_launch(void* const* d_in, const int* in_sizes, int n_in,
                              void* d_out, int out_size, void* d_ws, size_t ws_size,
                              hipStream_t stream) {
    const float* predicts = (const float*)d_in[0];
    const int*   labels   = (const int*)d_in[1];
    float*       out      = (float*)d_out;
    float*       partial  = (float*)d_ws;
    const int n = in_sizes[1];  // N rows

    const int grid = (n + ROWS_PER_BLOCK - 1) / ROWS_PER_BLOCK;  // 4096 for N=1M

    ce_stream_kernel<<<grid, BLOCK, 0, stream>>>(predicts, labels, partial, n);
    ce_final_kernel<<<1, 256, 0, stream>>>(partial, grid, -1.0f / (float)n, out);
}